// Round 7
// baseline (479.034 us; speedup 1.0000x reference)
//
#include <hip/hip_runtime.h>
#include <math.h>

#define H 2048
#define E 2048
#define ATTN 50
#define OUTSZ 32000
#define NBLK 1024   // 4 blocks/CU, 256 threads each -> 4096 waves

typedef float f32x4 __attribute__((ext_vector_type(4)));

__device__ inline float wave_reduce_sum(float v) {
  #pragma unroll
  for (int off = 32; off > 0; off >>= 1) v += __shfl_down(v, off, 64);
  return v;
}

__device__ inline float wave_reduce_max(float v) {
  #pragma unroll
  for (int off = 32; off > 0; off >>= 1) v = fmaxf(v, __shfl_down(v, off, 64));
  return v;
}

__device__ inline float sigmoidf_(float x) { return 1.f / (1.f + expf(-x)); }

__device__ inline f32x4 nt4(const float* p) {
  return __builtin_nontemporal_load((const f32x4*)p);
}
__device__ inline f32x4 ld4(const float* p) { return *(const f32x4*)p; }
__device__ inline float dot4(f32x4 a, f32x4 b) {
  return a.x * b.x + a.y * b.y + a.z * b.z + a.w * b.w;
}

// Grid barrier: 32 L1 counters (128B apart) -> 1 L2 counter -> generation flag.
// Generation-counting (safe for immediate reuse); release/acquire fences for
// cross-XCD visibility. Requires co-residency (cooperative launch).
__device__ inline void gbar(unsigned* bar, int b, int tid) {
  __syncthreads();
  if (tid == 0) {
    unsigned* l1 = bar + (b & 31) * 32;
    unsigned* l2 = bar + 1024;
    unsigned* gen = bar + 1056;
    unsigned g = __hip_atomic_load(gen, __ATOMIC_RELAXED, __HIP_MEMORY_SCOPE_AGENT);
    __threadfence();  // release this block's phase writes
    unsigned a = __hip_atomic_fetch_add(l1, 1u, __ATOMIC_RELAXED,
                                        __HIP_MEMORY_SCOPE_AGENT) + 1;
    if (a == NBLK / 32) {
      __hip_atomic_store(l1, 0u, __ATOMIC_RELAXED, __HIP_MEMORY_SCOPE_AGENT);
      unsigned a2 = __hip_atomic_fetch_add(l2, 1u, __ATOMIC_RELEASE,
                                           __HIP_MEMORY_SCOPE_AGENT) + 1;
      if (a2 == 32) {
        __hip_atomic_store(l2, 0u, __ATOMIC_RELAXED, __HIP_MEMORY_SCOPE_AGENT);
        __hip_atomic_store(gen, g + 1, __ATOMIC_RELEASE, __HIP_MEMORY_SCOPE_AGENT);
      }
    }
    while (__hip_atomic_load(gen, __ATOMIC_RELAXED, __HIP_MEMORY_SCOPE_AGENT) == g) {
      __builtin_amdgcn_s_sleep(1);
    }
    __threadfence();  // acquire: drop stale cached lines
  }
  __syncthreads();
}

__global__ __launch_bounds__(256, 4) void fused_k(
    const int* __restrict__ idx, const float* __restrict__ hidden,
    const float* __restrict__ cell, const float* __restrict__ enc,
    const float* __restrict__ embed, const float* __restrict__ attn_W,
    const float* __restrict__ attn_b, const float* __restrict__ comb_W,
    const float* __restrict__ comb_b, const float* __restrict__ Wih,
    const float* __restrict__ Whh, const float* __restrict__ bih,
    const float* __restrict__ bhh, const float* __restrict__ out_W,
    const float* __restrict__ out_b, float* __restrict__ out,
    float* __restrict__ ws, unsigned* __restrict__ bar) {
  const int b = blockIdx.x;
  const int tid = threadIdx.x;
  const int wid = tid >> 6;      // 0..3
  const int lane = tid & 63;
  const int gw = b * 4 + wid;    // global wave 0..4095

  float* scores = ws;              // 50
  float* xcat = ws + 64;           // 4096
  float* x0 = ws + 64 + 4096;      // 2048
  float* x1 = x0 + H;              // 2048
  float* x2 = x1 + H;              // 2048
  float* ghh = ws + 16384;         // 16384 ([2][4H], bhh folded in)
  float* logits = ws + 32768;      // 32000
  float* partials = ws + 65536;    // 2000 (1000 pairs)

  float* out_h = out + OUTSZ;
  float* out_c = out + OUTSZ + 2 * H;
  float* out_attnw = out + OUTSZ + 4 * H;

  __shared__ float sm[64];

  const float* embrow = embed + (size_t)idx[0] * E;

  // ---- Phase A: ghh (4 rows/wave, 2-row interleaved) + 50 score waves
  {
    #pragma unroll
    for (int p = 0; p < 4; p += 2) {
      int r0 = gw * 4 + p;               // even; pair never crosses layer bnd
      const float* w0 = Whh + (size_t)r0 * H;
      const float* w1 = w0 + H;
      const float* h = hidden + (r0 >> 13) * H;
      float a0 = 0.f, a1 = 0.f;
      #pragma unroll
      for (int k = lane * 4; k < H; k += 256) {
        f32x4 hv = ld4(h + k);
        a0 += dot4(nt4(w0 + k), hv);
        a1 += dot4(nt4(w1 + k), hv);
      }
      a0 = wave_reduce_sum(a0);
      a1 = wave_reduce_sum(a1);
      if (lane == 0) {
        ghh[r0] = a0 + bhh[r0];
        ghh[r0 + 1] = a1 + bhh[r0 + 1];
      }
    }
    if (gw >= 4096 - ATTN) {
      int t = gw - (4096 - ATTN);
      const float* row = attn_W + (size_t)t * (E + H);
      float a = 0.f;
      #pragma unroll
      for (int k = lane * 4; k < E; k += 256) {
        a += dot4(ld4(row + k), ld4(embrow + k));
        a += dot4(ld4(row + E + k), ld4(hidden + k));
      }
      a = wave_reduce_sum(a);
      if (lane == 0) scores[t] = a + attn_b[t];
    }
  }
  gbar(bar, b, tid);

  // ---- Phase B: softmax (redundant per block) + xcat slices (blocks 0..7)
  if (b < 8) {
    if (tid < 64) {
      float v = (tid < ATTN) ? scores[tid] : -INFINITY;
      float m = wave_reduce_max(v);
      m = __shfl(m, 0, 64);
      float e = (tid < ATTN) ? expf(v - m) : 0.f;
      float s = wave_reduce_sum(e);
      s = __shfl(s, 0, 64);
      if (tid < ATTN) {
        float ww = e / s;
        sm[tid] = ww;
        if (b == 0) out_attnw[tid] = ww;
      }
    }
    __syncthreads();
    int j = b * 256 + tid;
    float a = 0.f;
    #pragma unroll 10
    for (int t = 0; t < ATTN; t++) a += sm[t] * enc[t * H + j];
    xcat[j] = embrow[j];
    xcat[E + j] = a;
  }
  gbar(bar, b, tid);

  // ---- Phase C: comb matvec, wave-per-row (waves 0..2047), K=4096
  if (gw < H) {
    const float* row = comb_W + (size_t)gw * 4096;
    float a = 0.f;
    #pragma unroll
    for (int k = lane * 4; k < 4096; k += 256) a += dot4(nt4(row + k), ld4(xcat + k));
    a = wave_reduce_sum(a);
    if (lane == 0) x0[gw] = a + comb_b[gw];
  }
  gbar(bar, b, tid);

  // ---- Phases D/E: LSTM layers. Block handles units j0=b*2, j0+1; wave=gate;
  //      both units' dots interleaved (2 rows in flight), one syncthreads.
  #pragma unroll
  for (int layer = 0; layer < 2; layer++) {
    const float* Wl = Wih + (size_t)layer * 4 * H * H;
    const float* bl = bih + layer * 4 * H;
    const float* gl = ghh + layer * 4 * H;
    const float* x = (layer == 0) ? x0 : x1;
    const float* cl = cell + layer * H;
    float* ho = out_h + layer * H;
    float* co = out_c + layer * H;
    float* xn = (layer == 0) ? x1 : x2;
    int j0 = b * 2;
    int base = layer * 8;
    {
      const float* w0 = Wl + (size_t)(wid * H + j0) * H;
      const float* w1 = w0 + H;
      float a0 = 0.f, a1 = 0.f;
      #pragma unroll
      for (int k = lane * 4; k < H; k += 256) {
        f32x4 xv = ld4(x + k);
        a0 += dot4(nt4(w0 + k), xv);
        a1 += dot4(nt4(w1 + k), xv);
      }
      a0 = wave_reduce_sum(a0);
      a1 = wave_reduce_sum(a1);
      if (lane == 0) {
        sm[base + wid] = a0 + bl[wid * H + j0] + gl[wid * H + j0];
        sm[base + 4 + wid] = a1 + bl[wid * H + j0 + 1] + gl[wid * H + j0 + 1];
      }
    }
    __syncthreads();
    if (tid < 2) {
      int j = j0 + tid;
      float ig = sigmoidf_(sm[base + tid * 4 + 0]);
      float fg = sigmoidf_(sm[base + tid * 4 + 1]);
      float gg = tanhf(sm[base + tid * 4 + 2]);
      float og = sigmoidf_(sm[base + tid * 4 + 3]);
      float c = fg * cl[j] + ig * gg;
      float h = og * tanhf(c);
      ho[j] = h;
      co[j] = c;
      xn[j] = h;
    }
    gbar(bar, b, tid);
  }

  // ---- Phase F: out_W, 8 rows/wave (2-row interleaved x4), online LSE/wave,
  //      per-block partial (blocks 0..999)
  {
    float m = -INFINITY, s = 0.f;
    if (gw < 4000) {
      #pragma unroll
      for (int p = 0; p < 4; p++) {
        int r0 = gw * 8 + p * 2;
        const float* w0 = out_W + (size_t)r0 * H;
        const float* w1 = w0 + H;
        float a0 = 0.f, a1 = 0.f;
        #pragma unroll
        for (int k = lane * 4; k < H; k += 256) {
          f32x4 xv = ld4(x2 + k);
          a0 += dot4(nt4(w0 + k), xv);
          a1 += dot4(nt4(w1 + k), xv);
        }
        a0 = wave_reduce_sum(a0);
        a1 = wave_reduce_sum(a1);
        a0 = __shfl(a0, 0, 64);
        a1 = __shfl(a1, 0, 64);
        float v0 = a0 + out_b[r0];
        float v1 = a1 + out_b[r0 + 1];
        if (lane == 0) {
          logits[r0] = v0;
          logits[r0 + 1] = v1;
        }
        float nm = fmaxf(m, fmaxf(v0, v1));
        s = s * expf(m - nm) + expf(v0 - nm) + expf(v1 - nm);
        m = nm;
      }
      if (lane == 0) { sm[16 + wid * 2] = m; sm[16 + wid * 2 + 1] = s; }
    }
    __syncthreads();
    if (tid == 0 && b < 1000) {
      float M = -INFINITY, S = 0.f;
      #pragma unroll
      for (int q = 0; q < 4; q++) {
        float pm = sm[16 + q * 2], ps = sm[16 + q * 2 + 1];
        float nm = fmaxf(M, pm);
        S = S * expf(M - nm) + ps * expf(pm - nm);
        M = nm;
      }
      partials[2 * b] = M;
      partials[2 * b + 1] = S;
    }
  }
  gbar(bar, b, tid);

  // ---- Phase G: blocks 0..124 combine 1000 partials (redundant) + subtract
  if (b < 125) {
    if (tid < 64) {
      float m = -INFINITY, s = 0.f;
      for (int p = lane; p < 1000; p += 64) {
        float pm = partials[2 * p], ps = partials[2 * p + 1];
        float nm = fmaxf(m, pm);
        s = s * expf(m - nm) + ps * expf(pm - nm);
        m = nm;
      }
      #pragma unroll
      for (int off = 32; off > 0; off >>= 1) {
        float om = __shfl_down(m, off, 64);
        float os = __shfl_down(s, off, 64);
        float nm = fmaxf(m, om);
        s = s * expf(m - nm) + os * expf(om - nm);
        m = nm;
      }
      if (lane == 0) sm[0] = m + logf(s);
    }
    __syncthreads();
    float lse = sm[0];
    int i = b * 256 + tid;
    out[i] = logits[i] - lse;
  }
}

// ============================ fallback path (R4, proven 121.75us) ============

__global__ void k1_ghh_scores(const float* __restrict__ Whh, const float* __restrict__ bhh,
                              const float* __restrict__ hidden,
                              const int* __restrict__ idx, const float* __restrict__ embed_table,
                              const float* __restrict__ attn_W, const float* __restrict__ attn_b,
                              float* __restrict__ ghh, float* __restrict__ scores) {
  int b = blockIdx.x;
  if (b < 4096) {
    int r = b * 4 + (threadIdx.x >> 6);
    int lane = threadIdx.x & 63;
    int l = r >> 13;
    const float* w = Whh + (size_t)r * H;
    const float* h = hidden + l * H;
    float a = 0.f;
    #pragma unroll
    for (int k = lane * 4; k < H; k += 256) a += dot4(nt4(w + k), ld4(h + k));
    a = wave_reduce_sum(a);
    if (lane == 0) ghh[r] = a + bhh[r];
  } else {
    int t = b - 4096;
    int tid = threadIdx.x;
    const float* emb = embed_table + (size_t)idx[0] * E;
    const float* row = attn_W + (size_t)t * (E + H);
    float a = 0.f;
    #pragma unroll
    for (int it = 0; it < 4; it++) {
      int k = tid * 4 + it * 1024;
      f32x4 w4 = ld4(row + k);
      const float* src = (k < E) ? (emb + k) : (hidden + (k - E));
      a += dot4(w4, ld4(src));
    }
    a = wave_reduce_sum(a);
    __shared__ float red[4];
    if ((tid & 63) == 0) red[tid >> 6] = a;
    __syncthreads();
    if (tid == 0) scores[t] = red[0] + red[1] + red[2] + red[3] + attn_b[t];
  }
}

__global__ void attn_apply_k(const int* __restrict__ idx,
                             const float* __restrict__ embed_table,
                             const float* __restrict__ scores,
                             const float* __restrict__ enc,
                             float* __restrict__ xcat,
                             float* __restrict__ attnw_out) {
  __shared__ float w[ATTN];
  int tid = threadIdx.x;
  if (tid < 64) {
    float v = (tid < ATTN) ? scores[tid] : -INFINITY;
    float m = wave_reduce_max(v);
    m = __shfl(m, 0, 64);
    float e = (tid < ATTN) ? expf(v - m) : 0.f;
    float s = wave_reduce_sum(e);
    s = __shfl(s, 0, 64);
    if (tid < ATTN) {
      float ww = e / s;
      w[tid] = ww;
      if (blockIdx.x == 0) attnw_out[tid] = ww;
    }
  }
  __syncthreads();
  int j = blockIdx.x * 256 + tid;
  const float* emb = embed_table + (size_t)idx[0] * E;
  float a = 0.f;
  #pragma unroll 10
  for (int t = 0; t < ATTN; t++) a += w[t] * enc[t * H + j];
  xcat[j] = emb[j];
  xcat[E + j] = a;
}

__global__ void comb_k(const float* __restrict__ W, const float* __restrict__ xcat,
                       const float* __restrict__ bias, float* __restrict__ y) {
  int r = blockIdx.x;
  int tid = threadIdx.x;
  const float* row = W + (size_t)r * 4096;
  float a = 0.f;
  #pragma unroll
  for (int it = 0; it < 4; it++) {
    int k = tid * 4 + it * 1024;
    a += dot4(nt4(row + k), ld4(xcat + k));
  }
  a = wave_reduce_sum(a);
  __shared__ float red[4];
  if ((tid & 63) == 0) red[tid >> 6] = a;
  __syncthreads();
  if (tid == 0) y[r] = red[0] + red[1] + red[2] + red[3] + bias[r];
}

__global__ void lstm_k(const float* __restrict__ Wih, const float* __restrict__ bih,
                       const float* __restrict__ ghh,
                       const float* __restrict__ x, const float* __restrict__ cin,
                       float* __restrict__ hout, float* __restrict__ cout,
                       float* __restrict__ xnext) {
  int j = blockIdx.x;
  int g = threadIdx.x >> 6;
  int lane = threadIdx.x & 63;
  const float* w = Wih + (size_t)(g * H + j) * H;
  float a = 0.f;
  #pragma unroll
  for (int k = lane * 4; k < H; k += 256) a += dot4(nt4(w + k), ld4(x + k));
  a = wave_reduce_sum(a);
  __shared__ float gate[4];
  if (lane == 0) gate[g] = a + bih[g * H + j] + ghh[g * H + j];
  __syncthreads();
  if (threadIdx.x == 0) {
    float ig = sigmoidf_(gate[0]);
    float fg = sigmoidf_(gate[1]);
    float gg = tanhf(gate[2]);
    float og = sigmoidf_(gate[3]);
    float c = fg * cin[j] + ig * gg;
    float h = og * tanhf(c);
    hout[j] = h;
    cout[j] = c;
    xnext[j] = h;
  }
}

__global__ void outw_k(const float* __restrict__ W, const float* __restrict__ x,
                       const float* __restrict__ b,
                       float* __restrict__ logits, float* __restrict__ partials) {
  int wid = threadIdx.x >> 6;
  int lane = threadIdx.x & 63;
  int r0 = blockIdx.x * 8 + wid * 2;
  const float* w0 = W + (size_t)r0 * H;
  const float* w1 = w0 + H;
  float a0 = 0.f, a1 = 0.f;
  #pragma unroll
  for (int k = lane * 4; k < H; k += 256) {
    f32x4 x4 = ld4(x + k);
    a0 += dot4(nt4(w0 + k), x4);
    a1 += dot4(nt4(w1 + k), x4);
  }
  a0 = wave_reduce_sum(a0);
  a1 = wave_reduce_sum(a1);
  __shared__ float lv[8];
  if (lane == 0) {
    float v0 = a0 + b[r0];
    float v1 = a1 + b[r0 + 1];
    logits[r0] = v0;
    logits[r0 + 1] = v1;
    lv[wid * 2] = v0;
    lv[wid * 2 + 1] = v1;
  }
  __syncthreads();
  if (threadIdx.x == 0) {
    float m = -INFINITY;
    #pragma unroll
    for (int i = 0; i < 8; i++) m = fmaxf(m, lv[i]);
    float s = 0.f;
    #pragma unroll
    for (int i = 0; i < 8; i++) s += expf(lv[i] - m);
    partials[2 * blockIdx.x] = m;
    partials[2 * blockIdx.x + 1] = s;
  }
}

__global__ void lsm_out_k(const float* __restrict__ logits,
                          const float* __restrict__ partials,
                          float* __restrict__ out) {
  __shared__ float s_lse;
  int tid = threadIdx.x;
  if (tid < 64) {
    float m = -INFINITY;
    for (int p = tid; p < 4000; p += 64) m = fmaxf(m, partials[2 * p]);
    m = wave_reduce_max(m);
    m = __shfl(m, 0, 64);
    float s = 0.f;
    for (int p = tid; p < 4000; p += 64) s += partials[2 * p + 1] * expf(partials[2 * p] - m);
    s = wave_reduce_sum(s);
    if (tid == 0) s_lse = m + logf(s);
  }
  __syncthreads();
  int i = blockIdx.x * 256 + tid;
  out[i] = logits[i] - s_lse;
}

extern "C" void kernel_launch(void* const* d_in, const int* in_sizes, int n_in,
                              void* d_out, int out_size, void* d_ws, size_t ws_size,
                              hipStream_t stream) {
  const int* idx = (const int*)d_in[0];
  const float* hidden = (const float*)d_in[1];
  const float* cell = (const float*)d_in[2];
  const float* enc = (const float*)d_in[3];
  const float* embed = (const float*)d_in[4];
  const float* attn_W = (const float*)d_in[5];
  const float* attn_b = (const float*)d_in[6];
  const float* comb_W = (const float*)d_in[7];
  const float* comb_b = (const float*)d_in[8];
  const float* Wih = (const float*)d_in[9];
  const float* Whh = (const float*)d_in[10];
  const float* bih = (const float*)d_in[11];
  const float* bhh = (const float*)d_in[12];
  const float* out_W = (const float*)d_in[13];
  const float* out_b = (const float*)d_in[14];
  float* out = (float*)d_out;
  float* ws = (float*)d_ws;
  unsigned* bar = (unsigned*)(ws + 69632);

  // reset barrier state every call (deterministic across graph replays)
  hipMemsetAsync(bar, 0, 8192, stream);

  void* args[] = {(void*)&idx, (void*)&hidden, (void*)&cell, (void*)&enc,
                  (void*)&embed, (void*)&attn_W, (void*)&attn_b, (void*)&comb_W,
                  (void*)&comb_b, (void*)&Wih, (void*)&Whh, (void*)&bih,
                  (void*)&bhh, (void*)&out_W, (void*)&out_b, (void*)&out,
                  (void*)&ws, (void*)&bar};
  hipError_t err = hipLaunchCooperativeKernel((const void*)fused_k, dim3(NBLK),
                                              dim3(256), args, 0, stream);
  if (err == hipSuccess) return;

  // ---- fallback: 7-kernel chain (identical math) ----
  float* scores = ws;
  float* xcat = ws + 64;
  float* x0 = xcat + 4096;
  float* x1 = x0 + 2048;
  float* x2 = x1 + 2048;
  float* ghh = ws + 16384;
  float* logits = ws + 32768;
  float* partials = ws + 98304;

  float* out_h = out + 32000;
  float* out_c = out + 36096;
  float* out_attnw = out + 40192;

  k1_ghh_scores<<<4146, 256, 0, stream>>>(Whh, bhh, hidden, idx, embed,
                                          attn_W, attn_b, ghh, scores);
  attn_apply_k<<<8, 256, 0, stream>>>(idx, embed, scores, enc, xcat, out_attnw);
  comb_k<<<2048, 256, 0, stream>>>(comb_W, xcat, comb_b, x0);
  lstm_k<<<2048, 256, 0, stream>>>(Wih, bih, ghh, x0, cell, out_h, out_c, x1);
  lstm_k<<<2048, 256, 0, stream>>>(Wih + (size_t)4 * H * H, bih + 4 * H, ghh + 4 * H,
                                   x1, cell + H, out_h + H, out_c + H, x2);
  outw_k<<<4000, 256, 0, stream>>>(out_W, x2, out_b, logits, partials);
  lsm_out_k<<<125, 256, 0, stream>>>(logits, partials, out);
}

// Round 8
// 129.628 us; speedup vs baseline: 3.6954x; 3.6954x over previous
//
#include <hip/hip_runtime.h>
#include <math.h>

#define H 2048
#define E 2048
#define ATTN 50
#define OUTSZ 32000

typedef float f32x4 __attribute__((ext_vector_type(4)));

__device__ inline float wave_reduce_sum(float v) {
  #pragma unroll
  for (int off = 32; off > 0; off >>= 1) v += __shfl_down(v, off, 64);
  return v;
}

__device__ inline float wave_reduce_max(float v) {
  #pragma unroll
  for (int off = 32; off > 0; off >>= 1) v = fmaxf(v, __shfl_down(v, off, 64));
  return v;
}

__device__ inline float sigmoidf_(float x) { return 1.f / (1.f + expf(-x)); }

__device__ inline f32x4 ld4(const float* p) { return *(const f32x4*)p; }
__device__ inline float dot4(f32x4 a, f32x4 b) {
  return a.x * b.x + a.y * b.y + a.z * b.z + a.w * b.w;
}

// K1: blocks [0,1024): ghh — 4 rows per wave, 4-way interleaved accumulators.
//     blocks [1024,1074): attention scores (block per position, K=4096).
__global__ void k1_ghh_scores(const float* __restrict__ Whh, const float* __restrict__ bhh,
                              const float* __restrict__ hidden,
                              const int* __restrict__ idx, const float* __restrict__ embed_table,
                              const float* __restrict__ attn_W, const float* __restrict__ attn_b,
                              float* __restrict__ ghh, float* __restrict__ scores) {
  int b = blockIdx.x;
  int tid = threadIdx.x;
  int wid = tid >> 6;
  int lane = tid & 63;
  if (b < 1024) {
    int r0 = (b * 4 + wid) * 4;          // rows r0..r0+3, same layer (8192%4==0)
    const float* h = hidden + (r0 >> 13) * H;
    const float* w0 = Whh + (size_t)r0 * H;
    const float* w1 = w0 + H;
    const float* w2 = w1 + H;
    const float* w3 = w2 + H;
    float a0 = 0.f, a1 = 0.f, a2 = 0.f, a3 = 0.f;
    #pragma unroll
    for (int k = lane * 4; k < H; k += 256) {
      f32x4 hv = ld4(h + k);
      a0 += dot4(ld4(w0 + k), hv);
      a1 += dot4(ld4(w1 + k), hv);
      a2 += dot4(ld4(w2 + k), hv);
      a3 += dot4(ld4(w3 + k), hv);
    }
    a0 = wave_reduce_sum(a0);
    a1 = wave_reduce_sum(a1);
    a2 = wave_reduce_sum(a2);
    a3 = wave_reduce_sum(a3);
    if (lane == 0) {
      ghh[r0] = a0 + bhh[r0];
      ghh[r0 + 1] = a1 + bhh[r0 + 1];
      ghh[r0 + 2] = a2 + bhh[r0 + 2];
      ghh[r0 + 3] = a3 + bhh[r0 + 3];
    }
  } else {
    int t = b - 1024;                    // 0..49
    const float* emb = embed_table + (size_t)idx[0] * E;
    const float* row = attn_W + (size_t)t * (E + H);
    float a = 0.f;
    #pragma unroll
    for (int it = 0; it < 4; it++) {
      int k = tid * 4 + it * 1024;
      f32x4 w4 = ld4(row + k);
      const float* src = (k < E) ? (emb + k) : (hidden + (k - E));
      a += dot4(w4, ld4(src));
    }
    a = wave_reduce_sum(a);
    __shared__ float red[4];
    if (lane == 0) red[wid] = a;
    __syncthreads();
    if (tid == 0) scores[t] = red[0] + red[1] + red[2] + red[3] + attn_b[t];
  }
}

// K2: each block recomputes softmax over 50 scores (cheap), writes its slice of
// xcat = [emb, softmax @ enc]. Block 0 writes attn_weights output.
__global__ void attn_apply_k(const int* __restrict__ idx,
                             const float* __restrict__ embed_table,
                             const float* __restrict__ scores,
                             const float* __restrict__ enc,
                             float* __restrict__ xcat,
                             float* __restrict__ attnw_out) {
  __shared__ float w[ATTN];
  int tid = threadIdx.x;
  if (tid < 64) {
    float v = (tid < ATTN) ? scores[tid] : -INFINITY;
    float m = wave_reduce_max(v);
    m = __shfl(m, 0, 64);
    float e = (tid < ATTN) ? expf(v - m) : 0.f;
    float s = wave_reduce_sum(e);
    s = __shfl(s, 0, 64);
    if (tid < ATTN) {
      float ww = e / s;
      w[tid] = ww;
      if (blockIdx.x == 0) attnw_out[tid] = ww;
    }
  }
  __syncthreads();
  int j = blockIdx.x * 256 + tid;
  const float* emb = embed_table + (size_t)idx[0] * E;
  float a = 0.f;
  #pragma unroll 10
  for (int t = 0; t < ATTN; t++) a += w[t] * enc[t * H + j];
  xcat[j] = emb[j];
  xcat[E + j] = a;
}

// K3: comb matvec, block per row (K=4096)
__global__ void comb_k(const float* __restrict__ W, const float* __restrict__ xcat,
                       const float* __restrict__ bias, float* __restrict__ y) {
  int r = blockIdx.x;
  int tid = threadIdx.x;
  const float* row = W + (size_t)r * 4096;
  float a = 0.f;
  #pragma unroll
  for (int it = 0; it < 4; it++) {
    int k = tid * 4 + it * 1024;
    a += dot4(ld4(row + k), ld4(xcat + k));
  }
  a = wave_reduce_sum(a);
  __shared__ float red[4];
  if ((tid & 63) == 0) red[tid >> 6] = a;
  __syncthreads();
  if (tid == 0) y[r] = red[0] + red[1] + red[2] + red[3] + bias[r];
}

// K4/K5: LSTM with precomputed ghh. Block handles 2 units (j0, j0+1);
// wave g computes gate g for both, 2-row interleaved.
__global__ void lstm_k(const float* __restrict__ Wih, const float* __restrict__ bih,
                       const float* __restrict__ ghh,
                       const float* __restrict__ x, const float* __restrict__ cin,
                       float* __restrict__ hout, float* __restrict__ cout,
                       float* __restrict__ xnext) {
  int j0 = blockIdx.x * 2;
  int g = threadIdx.x >> 6;
  int lane = threadIdx.x & 63;
  const float* w0 = Wih + (size_t)(g * H + j0) * H;
  const float* w1 = w0 + H;
  float a0 = 0.f, a1 = 0.f;
  #pragma unroll
  for (int k = lane * 4; k < H; k += 256) {
    f32x4 xv = ld4(x + k);
    a0 += dot4(ld4(w0 + k), xv);
    a1 += dot4(ld4(w1 + k), xv);
  }
  a0 = wave_reduce_sum(a0);
  a1 = wave_reduce_sum(a1);
  __shared__ float gate[8];   // [unit][gate] = gate[u*4+g]
  if (lane == 0) {
    gate[g] = a0 + bih[g * H + j0] + ghh[g * H + j0];
    gate[4 + g] = a1 + bih[g * H + j0 + 1] + ghh[g * H + j0 + 1];
  }
  __syncthreads();
  if (threadIdx.x < 2) {
    int j = j0 + threadIdx.x;
    const float* gt = gate + threadIdx.x * 4;
    float ig = sigmoidf_(gt[0]);
    float fg = sigmoidf_(gt[1]);
    float gg = tanhf(gt[2]);
    float og = sigmoidf_(gt[3]);
    float c = fg * cin[j] + ig * gg;
    float h = og * tanhf(c);
    hout[j] = h;
    cout[j] = c;
    xnext[j] = h;
  }
}

// K6: out_W matvec, 4 rows per wave (16 rows/block) + fused per-block LSE partial
__global__ void outw_k(const float* __restrict__ W, const float* __restrict__ x,
                       const float* __restrict__ b,
                       float* __restrict__ logits, float* __restrict__ partials) {
  int wid = threadIdx.x >> 6;
  int lane = threadIdx.x & 63;
  int r0 = blockIdx.x * 16 + wid * 4;
  const float* w0 = W + (size_t)r0 * H;
  const float* w1 = w0 + H;
  const float* w2 = w1 + H;
  const float* w3 = w2 + H;
  float a0 = 0.f, a1 = 0.f, a2 = 0.f, a3 = 0.f;
  #pragma unroll
  for (int k = lane * 4; k < H; k += 256) {
    f32x4 xv = ld4(x + k);
    a0 += dot4(ld4(w0 + k), xv);
    a1 += dot4(ld4(w1 + k), xv);
    a2 += dot4(ld4(w2 + k), xv);
    a3 += dot4(ld4(w3 + k), xv);
  }
  a0 = wave_reduce_sum(a0);
  a1 = wave_reduce_sum(a1);
  a2 = wave_reduce_sum(a2);
  a3 = wave_reduce_sum(a3);
  __shared__ float lv[8];
  if (lane == 0) {
    float v0 = a0 + b[r0];
    float v1 = a1 + b[r0 + 1];
    float v2 = a2 + b[r0 + 2];
    float v3 = a3 + b[r0 + 3];
    logits[r0] = v0;
    logits[r0 + 1] = v1;
    logits[r0 + 2] = v2;
    logits[r0 + 3] = v3;
    float m = fmaxf(fmaxf(v0, v1), fmaxf(v2, v3));
    float s = expf(v0 - m) + expf(v1 - m) + expf(v2 - m) + expf(v3 - m);
    lv[wid * 2] = m;
    lv[wid * 2 + 1] = s;
  }
  __syncthreads();
  if (threadIdx.x == 0) {
    float M = -INFINITY, S = 0.f;
    #pragma unroll
    for (int q = 0; q < 4; q++) {
      float pm = lv[q * 2], ps = lv[q * 2 + 1];
      float nm = fmaxf(M, pm);
      S = S * expf(M - nm) + ps * expf(pm - nm);
      M = nm;
    }
    partials[2 * blockIdx.x] = M;
    partials[2 * blockIdx.x + 1] = S;
  }
}

// K7: combine 2000 partials (wave 0, redundant per block) then subtract
__global__ void lsm_out_k(const float* __restrict__ logits,
                          const float* __restrict__ partials,
                          float* __restrict__ out) {
  __shared__ float s_lse;
  int tid = threadIdx.x;
  if (tid < 64) {
    float m = -INFINITY, s = 0.f;
    for (int p = tid; p < 2000; p += 64) {
      float pm = partials[2 * p], ps = partials[2 * p + 1];
      float nm = fmaxf(m, pm);
      s = s * expf(m - nm) + ps * expf(pm - nm);
      m = nm;
    }
    #pragma unroll
    for (int off = 32; off > 0; off >>= 1) {
      float om = __shfl_down(m, off, 64);
      float os = __shfl_down(s, off, 64);
      float nm = fmaxf(m, om);
      s = s * expf(m - nm) + os * expf(om - nm);
      m = nm;
    }
    if (tid == 0) s_lse = m + logf(s);
  }
  __syncthreads();
  int i = blockIdx.x * 256 + tid;
  out[i] = logits[i] - s_lse;
}

extern "C" void kernel_launch(void* const* d_in, const int* in_sizes, int n_in,
                              void* d_out, int out_size, void* d_ws, size_t ws_size,
                              hipStream_t stream) {
  const int* idx = (const int*)d_in[0];
  const float* hidden = (const float*)d_in[1];   // [2,1,2048]
  const float* cell = (const float*)d_in[2];     // [2,1,2048]
  const float* enc = (const float*)d_in[3];      // [50,2048]
  const float* embed = (const float*)d_in[4];    // [32000,2048]
  const float* attn_W = (const float*)d_in[5];   // [50,4096]
  const float* attn_b = (const float*)d_in[6];   // [50]
  const float* comb_W = (const float*)d_in[7];   // [2048,4096]
  const float* comb_b = (const float*)d_in[8];   // [2048]
  const float* Wih = (const float*)d_in[9];      // [2,8192,2048]
  const float* Whh = (const float*)d_in[10];     // [2,8192,2048]
  const float* bih = (const float*)d_in[11];     // [2,8192]
  const float* bhh = (const float*)d_in[12];     // [2,8192]
  const float* out_W = (const float*)d_in[13];   // [32000,2048]
  const float* out_b = (const float*)d_in[14];   // [32000]
  float* out = (float*)d_out;

  // workspace layout (floats)
  float* ws = (float*)d_ws;
  float* scores = ws;             // 50
  float* xcat = ws + 64;          // 4096
  float* x0 = xcat + 4096;        // 2048
  float* x1 = x0 + 2048;          // 2048
  float* x2 = x1 + 2048;          // 2048
  float* ghh = ws + 16384;        // 16384 ([2][4H], bhh folded in)
  float* logits = ws + 32768;     // 32000
  float* partials = ws + 65536;   // 4000 (2000 pairs)

  // output layout: logits(32000) | h_stack(4096) | c_stack(4096) | attn_weights(50)
  float* out_h = out + 32000;
  float* out_c = out + 36096;
  float* out_attnw = out + 40192;

  k1_ghh_scores<<<1074, 256, 0, stream>>>(Whh, bhh, hidden, idx, embed,
                                          attn_W, attn_b, ghh, scores);
  attn_apply_k<<<8, 256, 0, stream>>>(idx, embed, scores, enc, xcat, out_attnw);
  comb_k<<<2048, 256, 0, stream>>>(comb_W, xcat, comb_b, x0);
  lstm_k<<<1024, 256, 0, stream>>>(Wih, bih, ghh, x0, cell, out_h, out_c, x1);
  lstm_k<<<1024, 256, 0, stream>>>(Wih + (size_t)4 * H * H, bih + 4 * H, ghh + 4 * H,
                                   x1, cell + H, out_h + H, out_c + H, x2);
  outw_k<<<2000, 256, 0, stream>>>(out_W, x2, out_b, logits, partials);
  lsm_out_k<<<125, 256, 0, stream>>>(logits, partials, out);
}